// Round 7
// baseline (2695.011 us; speedup 1.0000x reference)
//
#include <hip/hip_runtime.h>
#include <stddef.h>

// ---------- types / helpers ----------
using short8 = __attribute__((ext_vector_type(8))) short;
using f32x4  = __attribute__((ext_vector_type(4))) float;
using f32x16 = __attribute__((ext_vector_type(16))) float;
using u16x4  = __attribute__((ext_vector_type(4))) unsigned short;

__device__ __forceinline__ unsigned short cvt_bf16(float f) {
    unsigned u = __builtin_bit_cast(unsigned, f);
    u += 0x7fffu + ((u >> 16) & 1u);          // RNE
    return (unsigned short)(u >> 16);
}

__device__ __forceinline__ void gload_lds16(const void* g, void* l) {
    __builtin_amdgcn_global_load_lds(
        (const __attribute__((address_space(1))) unsigned*)g,
        (__attribute__((address_space(3))) unsigned*)l, 16, 0, 0);
}

#define MFMA16(a, b, c) __builtin_amdgcn_mfma_f32_16x16x32_bf16((a), (b), (c), 0, 0, 0)
#define MFMA32(a, b, c) __builtin_amdgcn_mfma_f32_32x32x16_bf16((a), (b), (c), 0, 0, 0)

// B=128, T=256, I=H=K=1024
// ---------- weight conversion: f32 -> bf16 ----------
__global__ __launch_bounds__(256) void convert_w(const float* __restrict__ Wi,
                                                 const float* __restrict__ Wh,
                                                 unsigned short* __restrict__ Wib,
                                                 unsigned short* __restrict__ Whb) {
    const float* src = blockIdx.y ? Wh : Wi;
    unsigned short* dst = blockIdx.y ? Whb : Wib;
    int base = blockIdx.x * 2048 + threadIdx.x * 8;
#pragma unroll
    for (int c = 0; c < 2; ++c) {
        float4 v = *(const float4*)(src + base + c * 4);
        u16x4 o;
        o.x = cvt_bf16(v.x); o.y = cvt_bf16(v.y); o.z = cvt_bf16(v.z); o.w = cvt_bf16(v.w);
        *(u16x4*)(dst + base + c * 4) = o;
    }
}

// ---------- h init + flag zero ----------
__global__ __launch_bounds__(256) void init_h(const float* __restrict__ hidden,
                                              unsigned short* __restrict__ h0,
                                              unsigned* __restrict__ flags) {
    int row = blockIdx.x;
    int tid = threadIdx.x;
    float4 v = *(const float4*)(hidden + (size_t)row * 1024 + tid * 4);
    u16x4 o;
    o.x = cvt_bf16(v.x); o.y = cvt_bf16(v.y); o.z = cvt_bf16(v.z); o.w = cvt_bf16(v.w);
    *(u16x4*)(h0 + (size_t)row * 1024 + tid * 4) = o;
    if (blockIdx.x == 0) {
        for (int i = tid; i < 512; i += 256) flags[i] = 0;
    }
}

// ---------- pre-GEMM: pre[t][b][n] = sum_k x[b][t][k] * Wi[n][k] + bi[n] ----------
__global__ __launch_bounds__(256) void pre_gemm(const float* __restrict__ x,
                                                const unsigned short* __restrict__ Wib,
                                                const float* __restrict__ bi,
                                                float* __restrict__ pre) {
    __shared__ unsigned short Alds[128 * 64];
    __shared__ unsigned short Blds[128 * 64];
    const int tid  = threadIdx.x;
    const int lane = tid & 63, wid = tid >> 6;
    const int wr = wid >> 1, wc = wid & 1;     // 2x2 waves, 64x64 each
    const int t  = blockIdx.y;                 // time index == M-tile
    const int n0 = blockIdx.x * 128;

    f32x4 acc[4][4] = {};

    for (int kt = 0; kt < 16; ++kt) {
        const int k0 = kt * 64;
        __syncthreads();
#pragma unroll
        for (int c = 0; c < 8; ++c) {
            int flat = c * 256 + tid;          // 0..2047
            int row = flat >> 4;               // 0..127  (batch b)
            int seg = flat & 15;               // 16 segs of 4 f32
            float4 v = *(const float4*)(x + (size_t)row * 262144 + (size_t)t * 1024 + k0 + seg * 4);
            u16x4 h;
            h.x = cvt_bf16(v.x); h.y = cvt_bf16(v.y); h.z = cvt_bf16(v.z); h.w = cvt_bf16(v.w);
            *(u16x4*)&Alds[row * 64 + seg * 4] = h;
        }
#pragma unroll
        for (int c = 0; c < 4; ++c) {
            int flat = c * 256 + tid;          // 0..1023
            int row = flat >> 3;               // 0..127
            int seg = flat & 7;                // 8 segs of 8 bf16
            gload_lds16(Wib + (size_t)(n0 + row) * 1024 + k0 + seg * 8, &Blds[flat * 8]);
        }
        __syncthreads();
#pragma unroll
        for (int ks = 0; ks < 2; ++ks) {
            short8 a[4], b[4];
#pragma unroll
            for (int i = 0; i < 4; ++i)
                a[i] = *(const short8*)&Alds[(wr * 64 + i * 16 + (lane & 15)) * 64 + ks * 32 + (lane >> 4) * 8];
#pragma unroll
            for (int j = 0; j < 4; ++j)
                b[j] = *(const short8*)&Blds[(wc * 64 + j * 16 + (lane & 15)) * 64 + ks * 32 + (lane >> 4) * 8];
#pragma unroll
            for (int i = 0; i < 4; ++i)
#pragma unroll
                for (int j = 0; j < 4; ++j)
                    acc[i][j] = MFMA16(a[i], b[j], acc[i][j]);
        }
    }
    const int rbase = wr * 64 + (lane >> 4) * 4;
    const int cbase = n0 + wc * 64 + (lane & 15);
#pragma unroll
    for (int i = 0; i < 4; ++i) {
#pragma unroll
        for (int j = 0; j < 4; ++j) {
            int n = cbase + j * 16;
            float bv = bi[n];
#pragma unroll
            for (int r = 0; r < 4; ++r) {
                int m = rbase + i * 16 + r;    // batch b
                pre[((size_t)t * 128 + m) * 1024 + n] = acc[i][j][r] + bv;
            }
        }
    }
}

// ---------- persistent scan kernel ----------
// 64 blocks x 256 threads. group g = bid&7 (8 blocks each); block covers
// 32 rows (g*32..) x 128 cols (ci*128..); each wave: 32 cols, FULL K=1024,
// Wh slice resident in 256 VGPRs. Operand-swapped MFMA (acc = C^T) so the
// per-lane accumulator maps to one batch-row x 16 n-values -> coalesced
// 8B h-stores, no cross-wave reduce. 2 syncthreads/step, 8-flag barrier.
__global__ __launch_bounds__(256, 1) void rnn_scan(const unsigned short* __restrict__ Whb,
                                                   const float* __restrict__ pre,
                                                   const float* __restrict__ bh,
                                                   unsigned short* __restrict__ ha,
                                                   unsigned short* __restrict__ hb,
                                                   float* __restrict__ out,
                                                   unsigned* __restrict__ flags) {
    __shared__ unsigned short Alds[32 * 1024];   // 64KB h-slice, XOR-swizzled

    const int tid  = threadIdx.x;
    const int lane = tid & 63, wid = tid >> 6;
    const int bid  = blockIdx.x;
    const int g    = bid & 7, ci = bid >> 3;     // group, column-block
    const int m0   = g * 32;
    const int nw   = ci * 128 + wid * 32;        // wave's 32 output cols
    const bool fwd = (g < 4);
    unsigned* gflags = flags + g * 8;            // 8 producer flags per group

    // resident Wh a-frags: rows nw..nw+31, all K=1024 -> 64 short8 (256 VGPR)
    short8 wfrag[64];
    {
        const unsigned short* bp = Whb + (size_t)(nw + (lane & 31)) * 1024 + (lane >> 5) * 8;
#pragma unroll
        for (int ks = 0; ks < 64; ++ks)
            wfrag[ks] = *(const short8*)(bp + ks * 16);
    }

    // lane constants (acc is C^T: col = lane&31 = m, regs -> n)
    const int m   = lane & 31;                   // batch-row within group
    const int mg  = m0 + m;
    const int b   = mg & 127;
    const int nhi = (lane >> 5) * 4;             // +4 for hi half-wave
    f32x4 bh4[4];
#pragma unroll
    for (int q = 0; q < 4; ++q)
        bh4[q] = *(const f32x4*)(bh + nw + nhi + q * 8);
    const float* prebase = pre + (size_t)b * 1024 + nw + nhi;
    float* outbase       = out + (size_t)b * 524288 + (fwd ? 0 : 1024) + nw + nhi;

    const char* arow = (const char*)Alds + m * 2048;
    const int   swz  = (m & 15) << 4;

    for (int s = 0; s < 256; ++s) {
        const unsigned short* hin = (s & 1) ? hb : ha;
        unsigned short* hout      = (s & 1) ? ha : hb;
        const int prow = fwd ? s : 255 - s;

        // pre tile prefetch (independent of h)
        f32x4 pv[4];
#pragma unroll
        for (int q = 0; q < 4; ++q)
            pv[q] = *(const f32x4*)(prebase + (size_t)prow * 131072 + q * 8);

        // per-wave poll of the 8 producer flags (no intra-block sync needed)
        if (s > 0) {
            int fuel = 1 << 22;
            unsigned v;
            do {
                v = __hip_atomic_load(&gflags[lane & 7], __ATOMIC_RELAXED,
                                      __HIP_MEMORY_SCOPE_AGENT);
            } while (!__all((int)(v >= (unsigned)s)) && --fuel);
        }

        // stage A: h rows m0..m0+31 (32 x 2048B), 8B/thread/row, swizzled ds_write
        {
            const unsigned long long* hsrc =
                (const unsigned long long*)(hin + (size_t)m0 * 1024);
            unsigned long long tmp[32];
#pragma unroll
            for (int i = 0; i < 32; ++i)
                tmp[i] = __hip_atomic_load(&hsrc[(size_t)i * 256 + tid],
                                           __ATOMIC_RELAXED, __HIP_MEMORY_SCOPE_AGENT);
            const int colswz = tid * 8;
#pragma unroll
            for (int i = 0; i < 32; ++i)
                *(unsigned long long*)((char*)Alds + i * 2048
                                       + (colswz ^ ((i & 15) << 4))) = tmp[i];
        }
        __syncthreads();

        // full-K MFMA: acc^T[n][m] += Wh[n][k] * h[m][k], 64 x 32x32x16
        f32x16 acc0 = {}, acc1 = {};
        const int khi = (lane >> 5) * 16;
#pragma unroll
        for (int ks = 0; ks < 64; ++ks) {
            short8 hf = *(const short8*)(arow + ((ks * 32 + khi) ^ swz));
            if (ks & 1) acc1 = MFMA32(wfrag[ks], hf, acc1);
            else        acc0 = MFMA32(wfrag[ks], hf, acc0);
        }
        f32x16 acc = acc0 + acc1;

        // epilogue: reg r = q*4+j -> n = nw + nhi + q*8 + j
        f32x4 ov[4];
#pragma unroll
        for (int q = 0; q < 4; ++q) {
            u16x4 hh;
#pragma unroll
            for (int j = 0; j < 4; ++j) {
                float xv = acc[q * 4 + j] + pv[q][j] + bh4[q][j];
                float hv = (5.0f * xv > 20.0f) ? xv : 0.2f * log1pf(__expf(5.0f * xv));
                ov[q][j] = hv;
                hh[j] = cvt_bf16(hv);
            }
            __hip_atomic_store((unsigned long long*)(hout + (size_t)mg * 1024 + nw + nhi + q * 8),
                               __builtin_bit_cast(unsigned long long, hh),
                               __ATOMIC_RELAXED, __HIP_MEMORY_SCOPE_AGENT);
        }
        asm volatile("s_waitcnt vmcnt(0)" ::: "memory");   // h stores acked
        __syncthreads();

        if (s < 255 && tid == 0)
            __hip_atomic_store(&gflags[ci], (unsigned)(s + 1),
                               __ATOMIC_RELAXED, __HIP_MEMORY_SCOPE_AGENT);

        // out stores after flag publish (off the critical path)
        const int tout = fwd ? ((239 - s) & 255) : s;
#pragma unroll
        for (int q = 0; q < 4; ++q)
            *(f32x4*)(outbase + (size_t)tout * 2048 + q * 8) = ov[q];
    }
}

// ---------- launch ----------
extern "C" void kernel_launch(void* const* d_in, const int* in_sizes, int n_in,
                              void* d_out, int out_size, void* d_ws, size_t ws_size,
                              hipStream_t stream) {
    const float* x      = (const float*)d_in[0];
    const float* hidden = (const float*)d_in[1];
    const float* Wi     = (const float*)d_in[2];
    const float* bi     = (const float*)d_in[3];
    const float* Wh     = (const float*)d_in[4];
    const float* bh     = (const float*)d_in[5];
    float* out = (float*)d_out;

    char* ws = (char*)d_ws;
    float*          pre = (float*)ws;                               // 128 MB
    unsigned short* Wib = (unsigned short*)(ws + 134217728);        // 2 MB
    unsigned short* Whb = (unsigned short*)(ws + 136314880);        // 2 MB
    unsigned short* ha  = (unsigned short*)(ws + 138412032);        // 512 KB
    unsigned short* hb  = (unsigned short*)(ws + 138936320);        // 512 KB
    unsigned*     flags = (unsigned*)(ws + 139460608);              // 2 KB

    convert_w<<<dim3(512, 2), 256, 0, stream>>>(Wi, Wh, Wib, Whb);
    init_h<<<256, 256, 0, stream>>>(hidden, ha, flags);
    pre_gemm<<<dim3(8, 256), 256, 0, stream>>>(x, Wib, bi, pre);
    rnn_scan<<<64, 256, 0, stream>>>(Whb, pre, bh, ha, hb, out, flags);
}